// Round 14
// baseline (208.989 us; speedup 1.0000x reference)
//
#include <hip/hip_runtime.h>
#include <hip/hip_fp16.h>

#define NF 128
#define TK 128

typedef _Float16 f16;
typedef f16 half8 __attribute__((ext_vector_type(8)));
typedef float floatx4 __attribute__((ext_vector_type(4)));

__device__ __forceinline__ unsigned okey(float f) {
  unsigned u = __float_as_uint(f);
  return (u & 0x80000000u) ? ~u : (u | 0x80000000u);
}

// ---------- zero workspace region ----------
__global__ void zero_kernel(uint4* __restrict__ dst, int n4) {
  int i = blockIdx.x * blockDim.x + threadIdx.x;
  int stride = gridDim.x * blockDim.x;
  uint4 z = make_uint4(0u, 0u, 0u, 0u);
  for (; i < n4; i += stride) dst[i] = z;
}

// ---------- scores (2 rows/thread) + key hist; edge blocks do ALL edge atomics ----------
__global__ void score_edge_kernel(const float* __restrict__ x, const float* __restrict__ p,
                                  float* __restrict__ score, unsigned* __restrict__ keys,
                                  unsigned* __restrict__ bins, int n, int nbScore,
                                  const int* __restrict__ ei, const float* __restrict__ ew,
                                  unsigned long long* __restrict__ cnt64,
                                  unsigned short* __restrict__ eslot, int E) {
  if ((int)blockIdx.x >= nbScore) {
    int e = ((int)blockIdx.x - nbScore) * 256 + (int)threadIdx.x;
    if (e < E) {
      int c = ei[E + e];
      unsigned fx = __float2uint_rn(ew[e] * 16777216.0f);  // 2^24 fixed point
      unsigned long long old =
          atomicAdd(&cnt64[c], ((unsigned long long)1 << 32) | (unsigned long long)fx);
      eslot[e] = (unsigned short)(old >> 32);
    }
    return;
  }
  int t = threadIdx.x;
  int rib = t >> 3;   // 0..31
  int l8 = t & 7;     // 8 lanes per row
  int rA = blockIdx.x * 64 + rib;
  int rB = rA + 32;
  bool vA = rA < n, vB = rB < n;
  const float4* pr = (const float4*)&p[l8 * 16];
  float4 p0 = pr[0], p1 = pr[1], p2 = pr[2], p3 = pr[3];
  float4 z4 = make_float4(0.f, 0.f, 0.f, 0.f);
  float4 a0 = z4, a1 = z4, a2 = z4, a3 = z4;
  float4 b0 = z4, b1 = z4, b2 = z4, b3 = z4;
  if (vA) {
    const float4* xa = (const float4*)&x[(size_t)rA * NF + l8 * 16];
    a0 = xa[0]; a1 = xa[1]; a2 = xa[2]; a3 = xa[3];
  }
  if (vB) {
    const float4* xb = (const float4*)&x[(size_t)rB * NF + l8 * 16];
    b0 = xb[0]; b1 = xb[1]; b2 = xb[2]; b3 = xb[3];
  }
  float dA = 0.f, dB = 0.f, pp = 0.f;
  dA = fmaf(a0.x, p0.x, dA); dA = fmaf(a0.y, p0.y, dA); dA = fmaf(a0.z, p0.z, dA); dA = fmaf(a0.w, p0.w, dA);
  dA = fmaf(a1.x, p1.x, dA); dA = fmaf(a1.y, p1.y, dA); dA = fmaf(a1.z, p1.z, dA); dA = fmaf(a1.w, p1.w, dA);
  dA = fmaf(a2.x, p2.x, dA); dA = fmaf(a2.y, p2.y, dA); dA = fmaf(a2.z, p2.z, dA); dA = fmaf(a2.w, p2.w, dA);
  dA = fmaf(a3.x, p3.x, dA); dA = fmaf(a3.y, p3.y, dA); dA = fmaf(a3.z, p3.z, dA); dA = fmaf(a3.w, p3.w, dA);
  dB = fmaf(b0.x, p0.x, dB); dB = fmaf(b0.y, p0.y, dB); dB = fmaf(b0.z, p0.z, dB); dB = fmaf(b0.w, p0.w, dB);
  dB = fmaf(b1.x, p1.x, dB); dB = fmaf(b1.y, p1.y, dB); dB = fmaf(b1.z, p1.z, dB); dB = fmaf(b1.w, p1.w, dB);
  dB = fmaf(b2.x, p2.x, dB); dB = fmaf(b2.y, p2.y, dB); dB = fmaf(b2.z, p2.z, dB); dB = fmaf(b2.w, p2.w, dB);
  dB = fmaf(b3.x, p3.x, dB); dB = fmaf(b3.y, p3.y, dB); dB = fmaf(b3.z, p3.z, dB); dB = fmaf(b3.w, p3.w, dB);
  pp = fmaf(p0.x, p0.x, pp); pp = fmaf(p0.y, p0.y, pp); pp = fmaf(p0.z, p0.z, pp); pp = fmaf(p0.w, p0.w, pp);
  pp = fmaf(p1.x, p1.x, pp); pp = fmaf(p1.y, p1.y, pp); pp = fmaf(p1.z, p1.z, pp); pp = fmaf(p1.w, p1.w, pp);
  pp = fmaf(p2.x, p2.x, pp); pp = fmaf(p2.y, p2.y, pp); pp = fmaf(p2.z, p2.z, pp); pp = fmaf(p2.w, p2.w, pp);
  pp = fmaf(p3.x, p3.x, pp); pp = fmaf(p3.y, p3.y, pp); pp = fmaf(p3.z, p3.z, pp); pp = fmaf(p3.w, p3.w, pp);
#pragma unroll
  for (int off = 4; off > 0; off >>= 1) {
    dA += __shfl_down(dA, off, 8);
    dB += __shfl_down(dB, off, 8);
    pp += __shfl_down(pp, off, 8);
  }
  if (l8 == 0) {
    float pni = 1.0f / sqrtf(pp);
    if (vA) {
      float s = tanhf(dA * pni);
      score[rA] = s;
      unsigned k = okey(s);
      keys[rA] = k;
      atomicAdd(&bins[k >> 16], 1u);
    }
    if (vB) {
      float s = tanhf(dB * pni);
      score[rB] = s;
      unsigned k = okey(s);
      keys[rB] = k;
      atomicAdd(&bins[k >> 16], 1u);
    }
  }
}

// ---------- block 0: findbin; blocks 1..nb: scan1 (block-local exclusive + dinv) ----------
#define SCAN_B 1024
__global__ __launch_bounds__(1024) void findbin_scan1_kernel(const unsigned* __restrict__ bins,
                                                             unsigned* __restrict__ thrB,
                                                             const unsigned long long* __restrict__ cnt64,
                                                             int* __restrict__ offL,
                                                             int* __restrict__ bsum,
                                                             float* __restrict__ dinv, int n) {
  int t = threadIdx.x;
  if (blockIdx.x == 0) {
    __shared__ unsigned csum[1024];
    unsigned hv[64];
    unsigned s = 0;
    const unsigned* bp = bins + t * 64;
#pragma unroll
    for (int b = 0; b < 64; ++b) { hv[b] = bp[b]; s += hv[b]; }
    csum[t] = s;
    __syncthreads();
    for (int st = 1; st < 1024; st <<= 1) {
      unsigned add = (t + st < 1024) ? csum[t + st] : 0u;
      __syncthreads();
      csum[t] += add;
      __syncthreads();
    }
    unsigned mySum = csum[t];
    unsigned above = (t == 1023) ? 0u : csum[t + 1];
    if (mySum >= (unsigned)TK && above < (unsigned)TK) {
      unsigned cum = above;
      int b = 63;
      for (; b > 0; --b) {
        unsigned h = hv[b];
        if (cum + h >= (unsigned)TK) break;
        cum += h;
      }
      thrB[0] = (unsigned)(t * 64 + b);
    }
    return;
  }
  __shared__ int sd[SCAN_B];
  int blk = blockIdx.x - 1;
  int i = blk * SCAN_B + t;
  int v = 0;
  if (i < n) {
    unsigned long long cv = cnt64[i];
    v = (int)(cv >> 32);
    float dsum = (float)((unsigned)cv) * (1.0f / 16777216.0f) + 1.0f;  // + self-loop
    dinv[i] = 1.0f / sqrtf(dsum);
  }
  sd[t] = v;
  __syncthreads();
  for (int s = 1; s < SCAN_B; s <<= 1) {
    int add = (t >= s) ? sd[t - s] : 0;
    __syncthreads();
    sd[t] += add;
    __syncthreads();
  }
  if (i <= n) offL[i] = sd[t] - v;  // block-local exclusive
  if (t == SCAN_B - 1) bsum[blk] = sd[t];
}

// ---------- block 0: scan2; blocks 1..: compact candidates ----------
__global__ __launch_bounds__(1024) void compact_scan2_kernel(const unsigned* __restrict__ keys,
                                                             const unsigned* __restrict__ thrB,
                                                             int* __restrict__ ncnt,
                                                             int* __restrict__ candIdx, int n,
                                                             const int* __restrict__ bsum,
                                                             int* __restrict__ bexc, int nb) {
  int t = threadIdx.x;
  if (blockIdx.x == 0) {
    if (t < 64) {  // requires nb <= 63 (N <= 64K)
      int v = (t < nb) ? bsum[t] : 0;
      int incl = v;
#pragma unroll
      for (int s = 1; s < 64; s <<= 1) {
        int u = __shfl_up(incl, s, 64);
        if (t >= s) incl += u;
      }
      if (t <= nb) bexc[t] = incl - v;
    }
    return;
  }
  int i = ((int)blockIdx.x - 1) * 1024 + t;
  if (i < n) {
    if ((keys[i] >> 16) >= thrB[0]) {
      int pos = atomicAdd(ncnt, 1);
      candIdx[pos] = i;
    }
  }
}

// ---------- block 0: exact top-K select; blocks 1..: fill CSR ----------
#define CCAP 6144
__global__ __launch_bounds__(1024) void select_fill_kernel(const unsigned* __restrict__ keys,
                                                           const int* __restrict__ candIdx,
                                                           const int* __restrict__ ncp,
                                                           const float* __restrict__ score,
                                                           int* __restrict__ perm,
                                                           float* __restrict__ tsc,
                                                           const int* __restrict__ ei,
                                                           const float* __restrict__ ew,
                                                           const float* __restrict__ dinv,
                                                           const int* __restrict__ offL,
                                                           const int* __restrict__ bexc,
                                                           const unsigned short* __restrict__ eslot,
                                                           unsigned* __restrict__ epair, int E) {
  int t = threadIdx.x;
  if (blockIdx.x > 0) {
    int e = ((int)blockIdx.x - 1) * 1024 + t;
    if (e < E) {
      int r = ei[e], c = ei[E + e];
      int pos = offL[c] + bexc[c >> 10] + (int)eslot[e];
      float cf = dinv[r] * ew[e] * dinv[c];
      unsigned hb = (unsigned)__builtin_bit_cast(unsigned short, __float2half(cf));
      epair[pos] = (unsigned)r | (hb << 16);
    }
    return;
  }
  __shared__ unsigned sk[CCAP];
  __shared__ int si[CCAP];
  int nc = ncp[0];
  int m = nc < CCAP ? nc : CCAP;
  for (int i = t; i < m; i += 1024) {
    int ci = candIdx[i];
    si[i] = ci;
    sk[i] = keys[ci];
  }
  __syncthreads();
  for (int ci = t; ci < nc; ci += 1024) {
    unsigned mk;
    int mi;
    if (ci < CCAP) { mk = sk[ci]; mi = si[ci]; }
    else { mi = candIdx[ci]; mk = keys[mi]; }
    int rank = 0;
    for (int j = 0; j < m; ++j) {
      unsigned kj = sk[j];
      int ij = si[j];
      rank += (kj > mk || (kj == mk && ij < mi)) ? 1 : 0;
    }
    for (int j = CCAP; j < nc; ++j) {
      int ij = candIdx[j];
      unsigned kj = keys[ij];
      rank += (kj > mk || (kj == mk && ij < mi)) ? 1 : 0;
    }
    if (rank < TK) {
      perm[rank] = mi;
      tsc[rank] = score[mi];
    }
  }
}

// ---------- GRU: block per row i, thread per col j; writes W transposed ----------
__global__ void gru_kernel(const float* __restrict__ x, const int* __restrict__ perm,
                           const float* __restrict__ tsc, const float* __restrict__ W0,
                           const float* __restrict__ w_ih, const float* __restrict__ w_hh,
                           const float* __restrict__ b_ih, const float* __restrict__ b_hh,
                           float* __restrict__ WT) {
  __shared__ float xs[NF], w0s[NF];
  int i = blockIdx.x, j = threadIdx.x;
  int pi = perm[i];
  float s = tsc[i];
  xs[j] = x[(size_t)pi * NF + j] * s;
  w0s[j] = W0[i * NF + j];
  __syncthreads();
  float gir = b_ih[j], giz = b_ih[NF + j], gin = b_ih[2 * NF + j];
  float ghr = b_hh[j], ghz = b_hh[NF + j], ghn = b_hh[2 * NF + j];
  const float* wr = w_ih + (size_t)j * NF;
  const float* wz = w_ih + (size_t)(NF + j) * NF;
  const float* wn = w_ih + (size_t)(2 * NF + j) * NF;
  const float* ur = w_hh + (size_t)j * NF;
  const float* uz = w_hh + (size_t)(NF + j) * NF;
  const float* un = w_hh + (size_t)(2 * NF + j) * NF;
#pragma unroll 4
  for (int k = 0; k < NF; ++k) {
    float xv = xs[k], wv = w0s[k];
    gir = fmaf(xv, wr[k], gir);
    giz = fmaf(xv, wz[k], giz);
    gin = fmaf(xv, wn[k], gin);
    ghr = fmaf(wv, ur[k], ghr);
    ghz = fmaf(wv, uz[k], ghz);
    ghn = fmaf(wv, un[k], ghn);
  }
  float r = 1.0f / (1.0f + expf(-(gir + ghr)));
  float z = 1.0f / (1.0f + expf(-(giz + ghz)));
  float nn = tanhf(gin + r * ghn);
  WT[(size_t)j * NF + i] = (1.0f - z) * nn + z * w0s[j];  // transposed: WT[n][k]
}

// ---------- aggregate: coalesced epair load per wave + WAVE-UNIFORM shfl broadcast ----------
__global__ void aggregate_kernel(const unsigned* __restrict__ epair, const int* __restrict__ offL,
                                 const int* __restrict__ bexc, const float* __restrict__ dinv,
                                 const uint4* __restrict__ xw4, unsigned* __restrict__ hh, int n) {
  int w = (int)((blockIdx.x * (size_t)blockDim.x + threadIdx.x) >> 6);
  if (w >= n) return;
  int lane = threadIdx.x & 63;
  int q = lane >> 4, l16 = lane & 15;
  int n0 = offL[w] + bexc[w >> 10];
  int n1 = offL[w + 1] + bexc[(w + 1) >> 10];
  float acc[8] = {0.f, 0.f, 0.f, 0.f, 0.f, 0.f, 0.f, 0.f};
  if (q == 0) {
    float dv = dinv[w];
    float c2 = dv * dv;  // self-loop: dinv[i]*1.0*dinv[i]
    uint4 su = xw4[(size_t)w * 16 + l16];
    float2 f0 = __half22float2(*(const __half2*)&su.x);
    float2 f1 = __half22float2(*(const __half2*)&su.y);
    float2 f2 = __half22float2(*(const __half2*)&su.z);
    float2 f3 = __half22float2(*(const __half2*)&su.w);
    acc[0] = c2 * f0.x; acc[1] = c2 * f0.y; acc[2] = c2 * f1.x; acc[3] = c2 * f1.y;
    acc[4] = c2 * f2.x; acc[5] = c2 * f2.y; acc[6] = c2 * f3.x; acc[7] = c2 * f3.y;
  }
  for (int base = n0; base < n1; base += 64) {  // wave-uniform outer loop
    int nc = n1 - base;
    if (nc > 64) nc = 64;
    unsigned pr = 0u;
    if (base + lane < n1) pr = epair[base + lane];  // one coalesced segment load per wave
    int nIter = (nc + 3) >> 2;                      // wave-uniform trip count
#pragma unroll 4
    for (int it = 0; it < nIter; ++it) {
      int j = it * 4 + q;
      bool act = j < nc;
      unsigned pj = __shfl(pr, act ? j : q, 64);  // ALL lanes execute the shfl
      if (act) {
        float cf = __half2float(__builtin_bit_cast(__half, (unsigned short)(pj >> 16)));
        uint4 u = xw4[(size_t)(pj & 0xFFFFu) * 16 + l16];
        float2 f0 = __half22float2(*(const __half2*)&u.x);
        float2 f1 = __half22float2(*(const __half2*)&u.y);
        float2 f2 = __half22float2(*(const __half2*)&u.z);
        float2 f3 = __half22float2(*(const __half2*)&u.w);
        acc[0] = fmaf(cf, f0.x, acc[0]); acc[1] = fmaf(cf, f0.y, acc[1]);
        acc[2] = fmaf(cf, f1.x, acc[2]); acc[3] = fmaf(cf, f1.y, acc[3]);
        acc[4] = fmaf(cf, f2.x, acc[4]); acc[5] = fmaf(cf, f2.y, acc[5]);
        acc[6] = fmaf(cf, f3.x, acc[6]); acc[7] = fmaf(cf, f3.y, acc[7]);
      }
    }
  }
#pragma unroll
  for (int j = 0; j < 8; ++j) {
    float a = acc[j];
    a += __shfl_xor(a, 16, 64);
    a += __shfl_xor(a, 32, 64);
    acc[j] = a;
  }
  if (q == 0) {
    __half2 h0 = __floats2half2_rn(fmaxf(acc[0], 0.f), fmaxf(acc[1], 0.f));
    __half2 h1 = __floats2half2_rn(fmaxf(acc[2], 0.f), fmaxf(acc[3], 0.f));
    __half2 h2 = __floats2half2_rn(fmaxf(acc[4], 0.f), fmaxf(acc[5], 0.f));
    __half2 h3 = __floats2half2_rn(fmaxf(acc[6], 0.f), fmaxf(acc[7], 0.f));
    uint4 o;
    o.x = *(unsigned*)&h0; o.y = *(unsigned*)&h1; o.z = *(unsigned*)&h2; o.w = *(unsigned*)&h3;
    *(uint4*)&hh[(size_t)w * 64 + l16 * 4] = o;
  }
}

// ---------- MFMA GEMM (generic): C[m][n] = sum_k A[m][k]*Bt[n][k] ----------
template <int HIN, int HOUT, int BIAS>
__global__ __launch_bounds__(256) void gemm_mfma_kernel(const void* __restrict__ Ap,
                                                        const float* __restrict__ Bt,
                                                        const float* __restrict__ bias,
                                                        void* __restrict__ Cp, int nrows) {
  __shared__ char ldsA[64 * 256];
  __shared__ char ldsB[128 * 256];
  const int t = threadIdx.x;
  const int row0 = blockIdx.x * 64;
  {
    const float2* B2 = (const float2*)Bt;
#pragma unroll
    for (int i = 0; i < 32; ++i) {
      int idx = i * 256 + t;
      int nn = idx >> 6, kp = idx & 63;
      float2 v = B2[idx];
      __half2 h = __floats2half2_rn(v.x, v.y);
      int byte = (nn * 256 + kp * 4) ^ ((nn & 7) << 4);
      *(unsigned*)&ldsB[byte] = *(unsigned*)&h;
    }
  }
  if (HIN) {
    const unsigned* Ah = (const unsigned*)Ap;
#pragma unroll
    for (int i = 0; i < 16; ++i) {
      int idx = i * 256 + t;
      int r = idx >> 6, cp = idx & 63;
      int gr = row0 + r;
      unsigned v = (gr < nrows) ? Ah[(size_t)gr * 64 + cp] : 0u;
      int byte = (r * 256 + cp * 4) ^ ((r & 7) << 4);
      *(unsigned*)&ldsA[byte] = v;
    }
  } else {
    const float2* A2 = (const float2*)Ap;
#pragma unroll
    for (int i = 0; i < 16; ++i) {
      int idx = i * 256 + t;
      int r = idx >> 6, cp = idx & 63;
      int gr = row0 + r;
      float2 v = make_float2(0.f, 0.f);
      if (gr < nrows) v = A2[(size_t)gr * 64 + cp];
      __half2 h = __floats2half2_rn(v.x, v.y);
      int byte = (r * 256 + cp * 4) ^ ((r & 7) << 4);
      *(unsigned*)&ldsA[byte] = *(unsigned*)&h;
    }
  }
  __syncthreads();
  const int wave = t >> 6, l = t & 63;
  const int wr0 = wave * 16;
  const int lm = l & 15, q = l >> 4;
  floatx4 acc[8];
#pragma unroll
  for (int nt = 0; nt < 8; ++nt) acc[nt] = (floatx4){0.f, 0.f, 0.f, 0.f};
#pragma unroll
  for (int ks = 0; ks < 4; ++ks) {
    int arow = wr0 + lm;
    half8 a = *(const half8*)&ldsA[(arow * 256 + ks * 64 + q * 16) ^ ((arow & 7) << 4)];
#pragma unroll
    for (int nt = 0; nt < 8; ++nt) {
      int nn = nt * 16 + lm;
      half8 b = *(const half8*)&ldsB[(nn * 256 + ks * 64 + q * 16) ^ ((nn & 7) << 4)];
      acc[nt] = __builtin_amdgcn_mfma_f32_16x16x32_f16(a, b, acc[nt], 0, 0, 0);
    }
  }
#pragma unroll
  for (int nt = 0; nt < 8; ++nt) {
    int col = nt * 16 + lm;
    float bv = BIAS ? bias[col] : 0.f;
#pragma unroll
    for (int r = 0; r < 4; ++r) {
      int gr = row0 + wr0 + q * 4 + r;
      if (gr < nrows) {
        float v = acc[nt][r] + bv;
        if (HOUT) ((__half*)Cp)[(size_t)gr * NF + col] = __float2half(v);
        else ((float*)Cp)[(size_t)gr * NF + col] = v;
      }
    }
  }
}

extern "C" void kernel_launch(void* const* d_in, const int* in_sizes, int n_in,
                              void* d_out, int out_size, void* d_ws, size_t ws_size,
                              hipStream_t stream) {
  const float* x = (const float*)d_in[0];
  const int* ei = (const int*)d_in[1];
  const float* ew = (const float*)d_in[2];
  const float* p = (const float*)d_in[3];
  const float* w_ih = (const float*)d_in[4];
  const float* w_hh = (const float*)d_in[5];
  const float* b_ih = (const float*)d_in[6];
  const float* b_hh = (const float*)d_in[7];
  const float* W0 = (const float*)d_in[8];
  const float* W_lin = (const float*)d_in[9];
  const float* b_lin = (const float*)d_in[10];
  float* out = (float*)d_out;

  const int N = in_sizes[0] / NF;  // 50000 (< 65536 required for 16-bit rows)
  const int E = in_sizes[1] / 2;   // 800000

  char* w = (char*)d_ws;
  unsigned* xwh = (unsigned*)w;                                 // N*64 (fp16 xw)
  unsigned* hh = xwh + (size_t)N * 64;                          // N*64 (fp16 relu(h))
  float* score = (float*)(hh + (size_t)N * 64);                 // N
  unsigned* keys = (unsigned*)(score + N);                      // N
  unsigned long long* cnt64 = (unsigned long long*)(keys + N);  // ZERO region: N x 8B
  unsigned* bins = (unsigned*)(cnt64 + N);                      // 65536
  int* ncnt = (int*)(bins + 65536);                             // 1 (end of ZERO region)
  float* dinv = (float*)(ncnt + 1);                             // N
  unsigned* thrB = (unsigned*)(dinv + N);                       // 1
  int* candIdx = (int*)(thrB + 1);                              // N
  int* offL = candIdx + N;                                      // N+1
  int* bsum = offL + N + 1;                                     // 64
  int* bexc = bsum + 64;                                        // 64
  unsigned short* eslot = (unsigned short*)(bexc + 64);         // E x 2B
  unsigned* epair = (unsigned*)(eslot + E);                     // E x 4B
  float* WevT = (float*)(epair + E);                            // 128*128
  int* perm = (int*)(WevT + NF * NF);                           // 128
  float* tsc = (float*)(perm + NF);                             // 128

  const int nb = (N + SCAN_B - 1) / SCAN_B;
  const int nbGemm = (N + 63) / 64;
  const int nbScore = (N + 63) / 64;
  const int nbEdge256 = (E + 255) / 256;
  const int nbEdge1024 = (E + 1023) / 1024;
  const int nOwnC = (N + 1023) / 1024;

  // zero region: cnt64 (N*8) + bins (256KB) + ncnt, padded to 16B
  const int n4zero = (N * 8 + 65536 * 4 + 4 + 15) / 16;

  zero_kernel<<<64, 1024, 0, stream>>>((uint4*)cnt64, n4zero);
  score_edge_kernel<<<nbScore + nbEdge256, 256, 0, stream>>>(x, p, score, keys, bins, N,
                                                             nbScore, ei, ew, cnt64, eslot, E);
  findbin_scan1_kernel<<<1 + nb, 1024, 0, stream>>>(bins, thrB, cnt64, offL, bsum, dinv, N);
  compact_scan2_kernel<<<1 + nOwnC, 1024, 0, stream>>>(keys, thrB, ncnt, candIdx, N,
                                                       bsum, bexc, nb);
  select_fill_kernel<<<1 + nbEdge1024, 1024, 0, stream>>>(keys, candIdx, ncnt, score, perm, tsc,
                                                          ei, ew, dinv, offL, bexc, eslot,
                                                          epair, E);
  gru_kernel<<<NF, NF, 0, stream>>>(x, perm, tsc, W0, w_ih, w_hh, b_ih, b_hh, WevT);
  gemm_mfma_kernel<0, 1, 0><<<nbGemm, 256, 0, stream>>>(x, WevT, nullptr, xwh, N);
  aggregate_kernel<<<(N + 3) / 4, 256, 0, stream>>>(epair, offL, bexc, dinv,
                                                    (const uint4*)xwh, hh, N);
  gemm_mfma_kernel<1, 0, 1><<<nbGemm, 256, 0, stream>>>(hh, W_lin, b_lin, out, N);
}

// Round 15
// 200.225 us; speedup vs baseline: 1.0438x; 1.0438x over previous
//
#include <hip/hip_runtime.h>
#include <hip/hip_fp16.h>

#define NF 128
#define TK 128

typedef _Float16 f16;
typedef f16 half8 __attribute__((ext_vector_type(8)));
typedef float floatx4 __attribute__((ext_vector_type(4)));

__device__ __forceinline__ unsigned okey(float f) {
  unsigned u = __float_as_uint(f);
  return (u & 0x80000000u) ? ~u : (u | 0x80000000u);
}

// edge-histogram slice: one edge per thread
__device__ __forceinline__ void edge_slice(const int* __restrict__ ei, const float* __restrict__ ew,
                                           unsigned long long* __restrict__ cnt64,
                                           unsigned short* __restrict__ eslot, int E, int e, int elim) {
  if (e < elim) {
    int c = ei[E + e];
    unsigned fx = __float2uint_rn(ew[e] * 16777216.0f);  // 2^24 fixed point
    unsigned long long old =
        atomicAdd(&cnt64[c], ((unsigned long long)1 << 32) | (unsigned long long)fx);
    eslot[e] = (unsigned short)(old >> 32);
  }
}

// ---------- zero workspace region ----------
__global__ void zero_kernel(uint4* __restrict__ dst, int n4) {
  int i = blockIdx.x * blockDim.x + threadIdx.x;
  int stride = gridDim.x * blockDim.x;
  uint4 z = make_uint4(0u, 0u, 0u, 0u);
  for (; i < n4; i += stride) dst[i] = z;
}

__device__ __forceinline__ uint4 pack8(float4 lo, float4 hi) {
  __half2 h0 = __floats2half2_rn(lo.x, lo.y);
  __half2 h1 = __floats2half2_rn(lo.z, lo.w);
  __half2 h2 = __floats2half2_rn(hi.x, hi.y);
  __half2 h3 = __floats2half2_rn(hi.z, hi.w);
  uint4 o;
  o.x = *(unsigned*)&h0; o.y = *(unsigned*)&h1; o.z = *(unsigned*)&h2; o.w = *(unsigned*)&h3;
  return o;
}

// ---------- scores: 2 rows/thread + fp16 x conversion; co-scheduled edge slice ----------
__global__ void score_edge_kernel(const float* __restrict__ x, const float* __restrict__ p,
                                  float* __restrict__ score, unsigned* __restrict__ keys,
                                  unsigned* __restrict__ bins, unsigned* __restrict__ xh,
                                  int n, int nbScore,
                                  const int* __restrict__ ei, const float* __restrict__ ew,
                                  unsigned long long* __restrict__ cnt64,
                                  unsigned short* __restrict__ eslot, int E, int ebase, int elim) {
  if ((int)blockIdx.x >= nbScore) {
    edge_slice(ei, ew, cnt64, eslot, E,
               ebase + ((int)blockIdx.x - nbScore) * 256 + (int)threadIdx.x, elim);
    return;
  }
  int t = threadIdx.x;
  int rib = t >> 3;   // 0..31
  int l8 = t & 7;     // 8 lanes per row
  int rA = blockIdx.x * 64 + rib;
  int rB = rA + 32;
  bool vA = rA < n, vB = rB < n;
  const float4* pr = (const float4*)&p[l8 * 16];
  float4 p0 = pr[0], p1 = pr[1], p2 = pr[2], p3 = pr[3];
  float4 z4 = make_float4(0.f, 0.f, 0.f, 0.f);
  float4 a0 = z4, a1 = z4, a2 = z4, a3 = z4;
  float4 b0 = z4, b1 = z4, b2 = z4, b3 = z4;
  if (vA) {
    const float4* xa = (const float4*)&x[(size_t)rA * NF + l8 * 16];
    a0 = xa[0]; a1 = xa[1]; a2 = xa[2]; a3 = xa[3];
  }
  if (vB) {
    const float4* xb = (const float4*)&x[(size_t)rB * NF + l8 * 16];
    b0 = xb[0]; b1 = xb[1]; b2 = xb[2]; b3 = xb[3];
  }
  // fp16 conversion of x for gemm1's A operand (xh aliases hh; read before aggregate writes)
  if (vA) {
    *(uint4*)&xh[(size_t)rA * 64 + l8 * 8] = pack8(a0, a1);
    *(uint4*)&xh[(size_t)rA * 64 + l8 * 8 + 4] = pack8(a2, a3);
  }
  if (vB) {
    *(uint4*)&xh[(size_t)rB * 64 + l8 * 8] = pack8(b0, b1);
    *(uint4*)&xh[(size_t)rB * 64 + l8 * 8 + 4] = pack8(b2, b3);
  }
  float dA = 0.f, dB = 0.f, pp = 0.f;
  dA = fmaf(a0.x, p0.x, dA); dA = fmaf(a0.y, p0.y, dA); dA = fmaf(a0.z, p0.z, dA); dA = fmaf(a0.w, p0.w, dA);
  dA = fmaf(a1.x, p1.x, dA); dA = fmaf(a1.y, p1.y, dA); dA = fmaf(a1.z, p1.z, dA); dA = fmaf(a1.w, p1.w, dA);
  dA = fmaf(a2.x, p2.x, dA); dA = fmaf(a2.y, p2.y, dA); dA = fmaf(a2.z, p2.z, dA); dA = fmaf(a2.w, p2.w, dA);
  dA = fmaf(a3.x, p3.x, dA); dA = fmaf(a3.y, p3.y, dA); dA = fmaf(a3.z, p3.z, dA); dA = fmaf(a3.w, p3.w, dA);
  dB = fmaf(b0.x, p0.x, dB); dB = fmaf(b0.y, p0.y, dB); dB = fmaf(b0.z, p0.z, dB); dB = fmaf(b0.w, p0.w, dB);
  dB = fmaf(b1.x, p1.x, dB); dB = fmaf(b1.y, p1.y, dB); dB = fmaf(b1.z, p1.z, dB); dB = fmaf(b1.w, p1.w, dB);
  dB = fmaf(b2.x, p2.x, dB); dB = fmaf(b2.y, p2.y, dB); dB = fmaf(b2.z, p2.z, dB); dB = fmaf(b2.w, p2.w, dB);
  dB = fmaf(b3.x, p3.x, dB); dB = fmaf(b3.y, p3.y, dB); dB = fmaf(b3.z, p3.z, dB); dB = fmaf(b3.w, p3.w, dB);
  pp = fmaf(p0.x, p0.x, pp); pp = fmaf(p0.y, p0.y, pp); pp = fmaf(p0.z, p0.z, pp); pp = fmaf(p0.w, p0.w, pp);
  pp = fmaf(p1.x, p1.x, pp); pp = fmaf(p1.y, p1.y, pp); pp = fmaf(p1.z, p1.z, pp); pp = fmaf(p1.w, p1.w, pp);
  pp = fmaf(p2.x, p2.x, pp); pp = fmaf(p2.y, p2.y, pp); pp = fmaf(p2.z, p2.z, pp); pp = fmaf(p2.w, p2.w, pp);
  pp = fmaf(p3.x, p3.x, pp); pp = fmaf(p3.y, p3.y, pp); pp = fmaf(p3.z, p3.z, pp); pp = fmaf(p3.w, p3.w, pp);
#pragma unroll
  for (int off = 4; off > 0; off >>= 1) {
    dA += __shfl_down(dA, off, 8);
    dB += __shfl_down(dB, off, 8);
    pp += __shfl_down(pp, off, 8);
  }
  if (l8 == 0) {
    float pni = 1.0f / sqrtf(pp);
    if (vA) {
      float s = tanhf(dA * pni);
      score[rA] = s;
      unsigned k = okey(s);
      keys[rA] = k;
      atomicAdd(&bins[k >> 16], 1u);
    }
    if (vB) {
      float s = tanhf(dB * pni);
      score[rB] = s;
      unsigned k = okey(s);
      keys[rB] = k;
      atomicAdd(&bins[k >> 16], 1u);
    }
  }
}

// ---------- findbin (block 0) + edge slice ----------
__global__ __launch_bounds__(1024) void findbin_edge_kernel(const unsigned* __restrict__ bins,
                                                            unsigned* __restrict__ thrB,
                                                            const int* __restrict__ ei,
                                                            const float* __restrict__ ew,
                                                            unsigned long long* __restrict__ cnt64,
                                                            unsigned short* __restrict__ eslot,
                                                            int E, int ebase, int elim) {
  if (blockIdx.x > 0) {
    edge_slice(ei, ew, cnt64, eslot, E, ebase + ((int)blockIdx.x - 1) * 1024 + (int)threadIdx.x, elim);
    return;
  }
  __shared__ unsigned csum[1024];
  int t = threadIdx.x;
  unsigned hv[64];
  unsigned s = 0;
  const unsigned* bp = bins + t * 64;
#pragma unroll
  for (int b = 0; b < 64; ++b) { hv[b] = bp[b]; s += hv[b]; }
  csum[t] = s;
  __syncthreads();
  for (int st = 1; st < 1024; st <<= 1) {
    unsigned add = (t + st < 1024) ? csum[t + st] : 0u;
    __syncthreads();
    csum[t] += add;
    __syncthreads();
  }
  unsigned mySum = csum[t];
  unsigned above = (t == 1023) ? 0u : csum[t + 1];
  if (mySum >= (unsigned)TK && above < (unsigned)TK) {
    unsigned cum = above;
    int b = 63;
    for (; b > 0; --b) {
      unsigned h = hv[b];
      if (cum + h >= (unsigned)TK) break;
      cum += h;
    }
    thrB[0] = (unsigned)(t * 64 + b);
  }
}

// ---------- compact candidates (blocks < nOwn) + edge slice ----------
__global__ __launch_bounds__(1024) void compact_edge_kernel(const unsigned* __restrict__ keys,
                                                            const unsigned* __restrict__ thrB,
                                                            int* __restrict__ ncnt,
                                                            int* __restrict__ candIdx, int n, int nOwn,
                                                            const int* __restrict__ ei,
                                                            const float* __restrict__ ew,
                                                            unsigned long long* __restrict__ cnt64,
                                                            unsigned short* __restrict__ eslot,
                                                            int E, int ebase, int elim) {
  if ((int)blockIdx.x >= nOwn) {
    edge_slice(ei, ew, cnt64, eslot, E,
               ebase + ((int)blockIdx.x - nOwn) * 1024 + (int)threadIdx.x, elim);
    return;
  }
  int i = blockIdx.x * 1024 + threadIdx.x;
  if (i < n) {
    if ((keys[i] >> 16) >= thrB[0]) {
      int pos = atomicAdd(ncnt, 1);
      candIdx[pos] = i;
    }
  }
}

// ---------- exact top-K select (block 0) + edge slice ----------
#define CCAP 6144
__global__ __launch_bounds__(1024) void select_edge_kernel(const unsigned* __restrict__ keys,
                                                           const int* __restrict__ candIdx,
                                                           const int* __restrict__ ncp,
                                                           const float* __restrict__ score,
                                                           int* __restrict__ perm,
                                                           float* __restrict__ tsc,
                                                           const int* __restrict__ ei,
                                                           const float* __restrict__ ew,
                                                           unsigned long long* __restrict__ cnt64,
                                                           unsigned short* __restrict__ eslot,
                                                           int E, int ebase, int elim) {
  if (blockIdx.x > 0) {
    edge_slice(ei, ew, cnt64, eslot, E, ebase + ((int)blockIdx.x - 1) * 1024 + (int)threadIdx.x, elim);
    return;
  }
  __shared__ unsigned sk[CCAP];
  __shared__ int si[CCAP];
  int nc = ncp[0];
  int t = threadIdx.x;
  int m = nc < CCAP ? nc : CCAP;
  for (int i = t; i < m; i += 1024) {
    int ci = candIdx[i];
    si[i] = ci;
    sk[i] = keys[ci];
  }
  __syncthreads();
  for (int ci = t; ci < nc; ci += 1024) {
    unsigned mk;
    int mi;
    if (ci < CCAP) { mk = sk[ci]; mi = si[ci]; }
    else { mi = candIdx[ci]; mk = keys[mi]; }
    int rank = 0;
    for (int j = 0; j < m; ++j) {
      unsigned kj = sk[j];
      int ij = si[j];
      rank += (kj > mk || (kj == mk && ij < mi)) ? 1 : 0;
    }
    for (int j = CCAP; j < nc; ++j) {
      int ij = candIdx[j];
      unsigned kj = keys[ij];
      rank += (kj > mk || (kj == mk && ij < mi)) ? 1 : 0;
    }
    if (rank < TK) {
      perm[rank] = mi;
      tsc[rank] = score[mi];
    }
  }
}

// ---------- GRU (blocks < 128, 128 thr) + edge slice; writes W transposed ----------
__global__ void gru_edge_kernel(const float* __restrict__ x, const int* __restrict__ perm,
                                const float* __restrict__ tsc, const float* __restrict__ W0,
                                const float* __restrict__ w_ih, const float* __restrict__ w_hh,
                                const float* __restrict__ b_ih, const float* __restrict__ b_hh,
                                float* __restrict__ WT,
                                const int* __restrict__ ei, const float* __restrict__ ew,
                                unsigned long long* __restrict__ cnt64,
                                unsigned short* __restrict__ eslot, int E, int ebase, int elim) {
  if ((int)blockIdx.x >= NF) {
    edge_slice(ei, ew, cnt64, eslot, E, ebase + ((int)blockIdx.x - NF) * 128 + (int)threadIdx.x, elim);
    return;
  }
  __shared__ float xs[NF], w0s[NF];
  int i = blockIdx.x, j = threadIdx.x;
  int pi = perm[i];
  float s = tsc[i];
  xs[j] = x[(size_t)pi * NF + j] * s;
  w0s[j] = W0[i * NF + j];
  __syncthreads();
  float gir = b_ih[j], giz = b_ih[NF + j], gin = b_ih[2 * NF + j];
  float ghr = b_hh[j], ghz = b_hh[NF + j], ghn = b_hh[2 * NF + j];
  const float* wr = w_ih + (size_t)j * NF;
  const float* wz = w_ih + (size_t)(NF + j) * NF;
  const float* wn = w_ih + (size_t)(2 * NF + j) * NF;
  const float* ur = w_hh + (size_t)j * NF;
  const float* uz = w_hh + (size_t)(NF + j) * NF;
  const float* un = w_hh + (size_t)(2 * NF + j) * NF;
#pragma unroll 4
  for (int k = 0; k < NF; ++k) {
    float xv = xs[k], wv = w0s[k];
    gir = fmaf(xv, wr[k], gir);
    giz = fmaf(xv, wz[k], giz);
    gin = fmaf(xv, wn[k], gin);
    ghr = fmaf(wv, ur[k], ghr);
    ghz = fmaf(wv, uz[k], ghz);
    ghn = fmaf(wv, un[k], ghn);
  }
  float r = 1.0f / (1.0f + expf(-(gir + ghr)));
  float z = 1.0f / (1.0f + expf(-(giz + ghz)));
  float nn = tanhf(gin + r * ghn);
  WT[(size_t)j * NF + i] = (1.0f - z) * nn + z * w0s[j];  // transposed: WT[n][k]
}

// ---------- scan over counts (block-local exclusive) + dinv ----------
#define SCAN_B 1024
__global__ __launch_bounds__(1024) void scan1_kernel(const unsigned long long* __restrict__ cnt64,
                                                     int* __restrict__ offL, int* __restrict__ bsum,
                                                     float* __restrict__ dinv, int n) {
  __shared__ int sd[SCAN_B];
  int t = threadIdx.x;
  int i = blockIdx.x * SCAN_B + t;
  int v = 0;
  if (i < n) {
    unsigned long long cv = cnt64[i];
    v = (int)(cv >> 32);
    float dsum = (float)((unsigned)cv) * (1.0f / 16777216.0f) + 1.0f;  // + self-loop
    dinv[i] = 1.0f / sqrtf(dsum);
  }
  sd[t] = v;
  __syncthreads();
  for (int s = 1; s < SCAN_B; s <<= 1) {
    int add = (t >= s) ? sd[t - s] : 0;
    __syncthreads();
    sd[t] += add;
    __syncthreads();
  }
  if (i <= n) offL[i] = sd[t] - v;  // block-local exclusive
  if (t == SCAN_B - 1) bsum[blockIdx.x] = sd[t];
}

// ---------- tiny: wave-scan of bsum -> bexc ----------
__global__ void scan2_kernel(const int* __restrict__ bsum, int* __restrict__ bexc, int nb) {
  int t = threadIdx.x;
  if (t < 64) {  // requires nb <= 63 (N <= 64K)
    int v = (t < nb) ? bsum[t] : 0;
    int incl = v;
#pragma unroll
    for (int s = 1; s < 64; s <<= 1) {
      int u = __shfl_up(incl, s, 64);
      if (t >= s) incl += u;
    }
    if (t <= nb) bexc[t] = incl - v;
  }
}

// ---------- GEMM1 (xh fp16 -> xw fp16) fused with CSR fill ----------
__global__ __launch_bounds__(256) void gemm1_fill_kernel(const unsigned* __restrict__ xh,
                                                         const float* __restrict__ Bt,
                                                         unsigned* __restrict__ Ch, int nrows,
                                                         int nbGemm,
                                                         const int* __restrict__ ei,
                                                         const float* __restrict__ ew,
                                                         const float* __restrict__ dinv,
                                                         const int* __restrict__ offL,
                                                         const int* __restrict__ bexc,
                                                         const unsigned short* __restrict__ eslot,
                                                         unsigned* __restrict__ epair, int E) {
  __shared__ char ldsA[64 * 256];
  __shared__ char ldsB[128 * 256];
  if ((int)blockIdx.x >= nbGemm) {
    int e = ((int)blockIdx.x - nbGemm) * 256 + (int)threadIdx.x;
    if (e < E) {
      int r = ei[e], c = ei[E + e];
      int pos = offL[c] + bexc[c >> 10] + (int)eslot[e];
      float cf = dinv[r] * ew[e] * dinv[c];
      unsigned hb = (unsigned)__builtin_bit_cast(unsigned short, __float2half(cf));
      epair[pos] = (unsigned)r | (hb << 16);
    }
    return;
  }
  const int t = threadIdx.x;
  const int row0 = blockIdx.x * 64;
  {  // stage Bt -> fp16 LDS
    const float2* B2 = (const float2*)Bt;
#pragma unroll
    for (int i = 0; i < 32; ++i) {
      int idx = i * 256 + t;
      int nn = idx >> 6, kp = idx & 63;
      float2 v = B2[idx];
      __half2 h = __floats2half2_rn(v.x, v.y);
      int byte = (nn * 256 + kp * 4) ^ ((nn & 7) << 4);
      *(unsigned*)&ldsB[byte] = *(unsigned*)&h;
    }
  }
  {  // stage A (already fp16)
#pragma unroll
    for (int i = 0; i < 16; ++i) {
      int idx = i * 256 + t;
      int r = idx >> 6, cp = idx & 63;
      int gr = row0 + r;
      unsigned v = (gr < nrows) ? xh[(size_t)gr * 64 + cp] : 0u;
      int byte = (r * 256 + cp * 4) ^ ((r & 7) << 4);
      *(unsigned*)&ldsA[byte] = v;
    }
  }
  __syncthreads();
  const int wave = t >> 6, l = t & 63;
  const int wr0 = wave * 16;
  const int lm = l & 15, q = l >> 4;
  floatx4 acc[8];
#pragma unroll
  for (int nt = 0; nt < 8; ++nt) acc[nt] = (floatx4){0.f, 0.f, 0.f, 0.f};
#pragma unroll
  for (int ks = 0; ks < 4; ++ks) {
    int arow = wr0 + lm;
    half8 a = *(const half8*)&ldsA[(arow * 256 + ks * 64 + q * 16) ^ ((arow & 7) << 4)];
#pragma unroll
    for (int nt = 0; nt < 8; ++nt) {
      int nn = nt * 16 + lm;
      half8 b = *(const half8*)&ldsB[(nn * 256 + ks * 64 + q * 16) ^ ((nn & 7) << 4)];
      acc[nt] = __builtin_amdgcn_mfma_f32_16x16x32_f16(a, b, acc[nt], 0, 0, 0);
    }
  }
#pragma unroll
  for (int nt = 0; nt < 8; ++nt) {
    int col = nt * 16 + lm;
#pragma unroll
    for (int r = 0; r < 4; ++r) {
      int gr = row0 + wr0 + q * 4 + r;
      if (gr < nrows)
        ((__half*)Ch)[(size_t)gr * NF + col] = __float2half(acc[nt][r]);
    }
  }
}

// ---------- aggregate: coalesced epair load per wave + WAVE-UNIFORM shfl broadcast ----------
__global__ void aggregate_kernel(const unsigned* __restrict__ epair, const int* __restrict__ offL,
                                 const int* __restrict__ bexc, const float* __restrict__ dinv,
                                 const uint4* __restrict__ xw4, unsigned* __restrict__ hh, int n) {
  int w = (int)((blockIdx.x * (size_t)blockDim.x + threadIdx.x) >> 6);
  if (w >= n) return;
  int lane = threadIdx.x & 63;
  int q = lane >> 4, l16 = lane & 15;
  int n0 = offL[w] + bexc[w >> 10];
  int n1 = offL[w + 1] + bexc[(w + 1) >> 10];
  float acc[8] = {0.f, 0.f, 0.f, 0.f, 0.f, 0.f, 0.f, 0.f};
  if (q == 0) {
    float dv = dinv[w];
    float c2 = dv * dv;  // self-loop: dinv[i]*1.0*dinv[i]
    uint4 su = xw4[(size_t)w * 16 + l16];
    float2 f0 = __half22float2(*(const __half2*)&su.x);
    float2 f1 = __half22float2(*(const __half2*)&su.y);
    float2 f2 = __half22float2(*(const __half2*)&su.z);
    float2 f3 = __half22float2(*(const __half2*)&su.w);
    acc[0] = c2 * f0.x; acc[1] = c2 * f0.y; acc[2] = c2 * f1.x; acc[3] = c2 * f1.y;
    acc[4] = c2 * f2.x; acc[5] = c2 * f2.y; acc[6] = c2 * f3.x; acc[7] = c2 * f3.y;
  }
  for (int base = n0; base < n1; base += 64) {  // wave-uniform outer loop
    int nc = n1 - base;
    if (nc > 64) nc = 64;
    unsigned pr = 0u;
    if (base + lane < n1) pr = epair[base + lane];  // one coalesced segment load per wave
    int nIter = (nc + 3) >> 2;                      // wave-uniform trip count
#pragma unroll 4
    for (int it = 0; it < nIter; ++it) {
      int j = it * 4 + q;
      bool act = j < nc;
      unsigned pj = __shfl(pr, act ? j : q, 64);  // ALL lanes execute the shfl
      if (act) {
        float cf = __half2float(__builtin_bit_cast(__half, (unsigned short)(pj >> 16)));
        uint4 u = xw4[(size_t)(pj & 0xFFFFu) * 16 + l16];
        float2 f0 = __half22float2(*(const __half2*)&u.x);
        float2 f1 = __half22float2(*(const __half2*)&u.y);
        float2 f2 = __half22float2(*(const __half2*)&u.z);
        float2 f3 = __half22float2(*(const __half2*)&u.w);
        acc[0] = fmaf(cf, f0.x, acc[0]); acc[1] = fmaf(cf, f0.y, acc[1]);
        acc[2] = fmaf(cf, f1.x, acc[2]); acc[3] = fmaf(cf, f1.y, acc[3]);
        acc[4] = fmaf(cf, f2.x, acc[4]); acc[5] = fmaf(cf, f2.y, acc[5]);
        acc[6] = fmaf(cf, f3.x, acc[6]); acc[7] = fmaf(cf, f3.y, acc[7]);
      }
    }
  }
#pragma unroll
  for (int j = 0; j < 8; ++j) {
    float a = acc[j];
    a += __shfl_xor(a, 16, 64);
    a += __shfl_xor(a, 32, 64);
    acc[j] = a;
  }
  if (q == 0) {
    __half2 h0 = __floats2half2_rn(fmaxf(acc[0], 0.f), fmaxf(acc[1], 0.f));
    __half2 h1 = __floats2half2_rn(fmaxf(acc[2], 0.f), fmaxf(acc[3], 0.f));
    __half2 h2 = __floats2half2_rn(fmaxf(acc[4], 0.f), fmaxf(acc[5], 0.f));
    __half2 h3 = __floats2half2_rn(fmaxf(acc[6], 0.f), fmaxf(acc[7], 0.f));
    uint4 o;
    o.x = *(unsigned*)&h0; o.y = *(unsigned*)&h1; o.z = *(unsigned*)&h2; o.w = *(unsigned*)&h3;
    *(uint4*)&hh[(size_t)w * 64 + l16 * 4] = o;
  }
}

// ---------- MFMA GEMM (generic): C[m][n] = sum_k A[m][k]*Bt[n][k] ----------
template <int HIN, int HOUT, int BIAS>
__global__ __launch_bounds__(256) void gemm_mfma_kernel(const void* __restrict__ Ap,
                                                        const float* __restrict__ Bt,
                                                        const float* __restrict__ bias,
                                                        void* __restrict__ Cp, int nrows) {
  __shared__ char ldsA[64 * 256];
  __shared__ char ldsB[128 * 256];
  const int t = threadIdx.x;
  const int row0 = blockIdx.x * 64;
  {
    const float2* B2 = (const float2*)Bt;
#pragma unroll
    for (int i = 0; i < 32; ++i) {
      int idx = i * 256 + t;
      int nn = idx >> 6, kp = idx & 63;
      float2 v = B2[idx];
      __half2 h = __floats2half2_rn(v.x, v.y);
      int byte = (nn * 256 + kp * 4) ^ ((nn & 7) << 4);
      *(unsigned*)&ldsB[byte] = *(unsigned*)&h;
    }
  }
  if (HIN) {
    const unsigned* Ah = (const unsigned*)Ap;
#pragma unroll
    for (int i = 0; i < 16; ++i) {
      int idx = i * 256 + t;
      int r = idx >> 6, cp = idx & 63;
      int gr = row0 + r;
      unsigned v = (gr < nrows) ? Ah[(size_t)gr * 64 + cp] : 0u;
      int byte = (r * 256 + cp * 4) ^ ((r & 7) << 4);
      *(unsigned*)&ldsA[byte] = v;
    }
  } else {
    const float2* A2 = (const float2*)Ap;
#pragma unroll
    for (int i = 0; i < 16; ++i) {
      int idx = i * 256 + t;
      int r = idx >> 6, cp = idx & 63;
      int gr = row0 + r;
      float2 v = make_float2(0.f, 0.f);
      if (gr < nrows) v = A2[(size_t)gr * 64 + cp];
      __half2 h = __floats2half2_rn(v.x, v.y);
      int byte = (r * 256 + cp * 4) ^ ((r & 7) << 4);
      *(unsigned*)&ldsA[byte] = *(unsigned*)&h;
    }
  }
  __syncthreads();
  const int wave = t >> 6, l = t & 63;
  const int wr0 = wave * 16;
  const int lm = l & 15, q = l >> 4;
  floatx4 acc[8];
#pragma unroll
  for (int nt = 0; nt < 8; ++nt) acc[nt] = (floatx4){0.f, 0.f, 0.f, 0.f};
#pragma unroll
  for (int ks = 0; ks < 4; ++ks) {
    int arow = wr0 + lm;
    half8 a = *(const half8*)&ldsA[(arow * 256 + ks * 64 + q * 16) ^ ((arow & 7) << 4)];
#pragma unroll
    for (int nt = 0; nt < 8; ++nt) {
      int nn = nt * 16 + lm;
      half8 b = *(const half8*)&ldsB[(nn * 256 + ks * 64 + q * 16) ^ ((nn & 7) << 4)];
      acc[nt] = __builtin_amdgcn_mfma_f32_16x16x32_f16(a, b, acc[nt], 0, 0, 0);
    }
  }
#pragma unroll
  for (int nt = 0; nt < 8; ++nt) {
    int col = nt * 16 + lm;
    float bv = BIAS ? bias[col] : 0.f;
#pragma unroll
    for (int r = 0; r < 4; ++r) {
      int gr = row0 + wr0 + q * 4 + r;
      if (gr < nrows) {
        float v = acc[nt][r] + bv;
        if (HOUT) ((__half*)Cp)[(size_t)gr * NF + col] = __float2half(v);
        else ((float*)Cp)[(size_t)gr * NF + col] = v;
      }
    }
  }
}

extern "C" void kernel_launch(void* const* d_in, const int* in_sizes, int n_in,
                              void* d_out, int out_size, void* d_ws, size_t ws_size,
                              hipStream_t stream) {
  const float* x = (const float*)d_in[0];
  const int* ei = (const int*)d_in[1];
  const float* ew = (const float*)d_in[2];
  const float* p = (const float*)d_in[3];
  const float* w_ih = (const float*)d_in[4];
  const float* w_hh = (const float*)d_in[5];
  const float* b_ih = (const float*)d_in[6];
  const float* b_hh = (const float*)d_in[7];
  const float* W0 = (const float*)d_in[8];
  const float* W_lin = (const float*)d_in[9];
  const float* b_lin = (const float*)d_in[10];
  float* out = (float*)d_out;

  const int N = in_sizes[0] / NF;  // 50000 (< 65536 required for 16-bit rows)
  const int E = in_sizes[1] / 2;   // 800000

  char* w = (char*)d_ws;
  unsigned* xwh = (unsigned*)w;                                 // N*64 (fp16 xw)
  unsigned* hh = xwh + (size_t)N * 64;                          // N*64 (fp16 relu(h)); ALSO xh (fp16 x) earlier in pipeline
  float* score = (float*)(hh + (size_t)N * 64);                 // N
  unsigned* keys = (unsigned*)(score + N);                      // N
  unsigned long long* cnt64 = (unsigned long long*)(keys + N);  // ZERO region: N x 8B
  unsigned* bins = (unsigned*)(cnt64 + N);                      // 65536
  int* ncnt = (int*)(bins + 65536);                             // 1 (end of ZERO region)
  float* dinv = (float*)(ncnt + 1);                             // N
  unsigned* thrB = (unsigned*)(dinv + N);                       // 1
  int* candIdx = (int*)(thrB + 1);                              // N
  int* offL = candIdx + N;                                      // N+1
  int* bsum = offL + N + 1;                                     // 64
  int* bexc = bsum + 64;                                        // 64
  unsigned short* eslot = (unsigned short*)(bexc + 64);         // E x 2B
  unsigned* epair = (unsigned*)(eslot + E);                     // E x 4B
  float* WevT = (float*)(epair + E);                            // 128*128
  int* perm = (int*)(WevT + NF * NF);                           // 128
  float* tsc = (float*)(perm + NF);                             // 128
  unsigned* xh = hh;  // alias: xh written by score, fully consumed by gemm1 before aggregate writes hh

  const int nb = (N + SCAN_B - 1) / SCAN_B;
  const int nbEdge = (E + 255) / 256;
  const int nbGemm = (N + 63) / 64;
  const int nbScore = (N + 63) / 64;
  const int nOwnC = (N + 1023) / 1024;

  // edge-slice partition: 45% rides with score, remaining 55% over 4 stages
  const int eA1 = (int)(((long long)E * 9) / 20);
  const int perR = (E - eA1 + 3) / 4;
  const int eB1 = (eA1 + perR < E) ? eA1 + perR : E;
  const int eC1 = (eB1 + perR < E) ? eB1 + perR : E;
  const int eD1 = (eC1 + perR < E) ? eC1 + perR : E;
  const int bSA = (eA1 + 255) / 256;
  const int bSB = (eB1 - eA1 + 1023) / 1024;
  const int bSC = (eC1 - eB1 + 1023) / 1024;
  const int bSD = (eD1 - eC1 + 1023) / 1024;
  const int bSE = (E - eD1 + 127) / 128;

  // zero region: cnt64 (N*8) + bins (256KB) + ncnt, padded to 16B
  const int n4zero = (N * 8 + 65536 * 4 + 4 + 15) / 16;

  zero_kernel<<<64, 1024, 0, stream>>>((uint4*)cnt64, n4zero);
  score_edge_kernel<<<nbScore + bSA, 256, 0, stream>>>(x, p, score, keys, bins, xh, N, nbScore,
                                                       ei, ew, cnt64, eslot, E, 0, eA1);
  findbin_edge_kernel<<<1 + bSB, 1024, 0, stream>>>(bins, thrB, ei, ew, cnt64, eslot, E, eA1, eB1);
  compact_edge_kernel<<<nOwnC + bSC, 1024, 0, stream>>>(keys, thrB, ncnt, candIdx, N, nOwnC,
                                                        ei, ew, cnt64, eslot, E, eB1, eC1);
  select_edge_kernel<<<1 + bSD, 1024, 0, stream>>>(keys, candIdx, ncnt, score, perm, tsc,
                                                   ei, ew, cnt64, eslot, E, eC1, eD1);
  gru_edge_kernel<<<NF + bSE, NF, 0, stream>>>(x, perm, tsc, W0, w_ih, w_hh, b_ih, b_hh, WevT,
                                               ei, ew, cnt64, eslot, E, eD1, E);
  scan1_kernel<<<nb, SCAN_B, 0, stream>>>(cnt64, offL, bsum, dinv, N);
  scan2_kernel<<<1, 64, 0, stream>>>(bsum, bexc, nb);
  gemm1_fill_kernel<<<nbGemm + nbEdge, 256, 0, stream>>>(xh, WevT, xwh, N, nbGemm,
                                                         ei, ew, dinv, offL, bexc, eslot, epair, E);
  aggregate_kernel<<<(N + 3) / 4, 256, 0, stream>>>(epair, offL, bexc, dinv,
                                                    (const uint4*)xwh, hh, N);
  gemm_mfma_kernel<1, 0, 1><<<nbGemm, 256, 0, stream>>>(hh, W_lin, b_lin, out, N);
}

// Round 16
// 197.495 us; speedup vs baseline: 1.0582x; 1.0138x over previous
//
#include <hip/hip_runtime.h>
#include <hip/hip_fp16.h>

#define NF 128
#define TK 128

typedef _Float16 f16;
typedef f16 half8 __attribute__((ext_vector_type(8)));
typedef float floatx4 __attribute__((ext_vector_type(4)));

__device__ __forceinline__ unsigned okey(float f) {
  unsigned u = __float_as_uint(f);
  return (u & 0x80000000u) ? ~u : (u | 0x80000000u);
}

// edge-histogram slice: one edge per thread
__device__ __forceinline__ void edge_slice(const int* __restrict__ ei, const float* __restrict__ ew,
                                           unsigned long long* __restrict__ cnt64,
                                           unsigned short* __restrict__ eslot, int E, int e, int elim) {
  if (e < elim) {
    int c = ei[E + e];
    unsigned fx = __float2uint_rn(ew[e] * 16777216.0f);  // 2^24 fixed point
    unsigned long long old =
        atomicAdd(&cnt64[c], ((unsigned long long)1 << 32) | (unsigned long long)fx);
    eslot[e] = (unsigned short)(old >> 32);
  }
}

// ---------- zero workspace region ----------
__global__ void zero_kernel(uint4* __restrict__ dst, int n4) {
  int i = blockIdx.x * blockDim.x + threadIdx.x;
  int stride = gridDim.x * blockDim.x;
  uint4 z = make_uint4(0u, 0u, 0u, 0u);
  for (; i < n4; i += stride) dst[i] = z;
}

// ---------- scores: 2 rows/thread, 8 outstanding loads; co-scheduled edge slice ----------
__global__ void score_edge_kernel(const float* __restrict__ x, const float* __restrict__ p,
                                  float* __restrict__ score, unsigned* __restrict__ keys,
                                  unsigned* __restrict__ bins, int n, int nbScore,
                                  const int* __restrict__ ei, const float* __restrict__ ew,
                                  unsigned long long* __restrict__ cnt64,
                                  unsigned short* __restrict__ eslot, int E, int ebase, int elim) {
  if ((int)blockIdx.x >= nbScore) {
    edge_slice(ei, ew, cnt64, eslot, E,
               ebase + ((int)blockIdx.x - nbScore) * 256 + (int)threadIdx.x, elim);
    return;
  }
  int t = threadIdx.x;
  int rib = t >> 3;   // 0..31
  int l8 = t & 7;     // 8 lanes per row
  int rA = blockIdx.x * 64 + rib;
  int rB = rA + 32;
  bool vA = rA < n, vB = rB < n;
  const float4* pr = (const float4*)&p[l8 * 16];
  float4 p0 = pr[0], p1 = pr[1], p2 = pr[2], p3 = pr[3];
  float4 z4 = make_float4(0.f, 0.f, 0.f, 0.f);
  float4 a0 = z4, a1 = z4, a2 = z4, a3 = z4;
  float4 b0 = z4, b1 = z4, b2 = z4, b3 = z4;
  if (vA) {
    const float4* xa = (const float4*)&x[(size_t)rA * NF + l8 * 16];
    a0 = xa[0]; a1 = xa[1]; a2 = xa[2]; a3 = xa[3];
  }
  if (vB) {
    const float4* xb = (const float4*)&x[(size_t)rB * NF + l8 * 16];
    b0 = xb[0]; b1 = xb[1]; b2 = xb[2]; b3 = xb[3];
  }
  float dA = 0.f, dB = 0.f, pp = 0.f;
  dA = fmaf(a0.x, p0.x, dA); dA = fmaf(a0.y, p0.y, dA); dA = fmaf(a0.z, p0.z, dA); dA = fmaf(a0.w, p0.w, dA);
  dA = fmaf(a1.x, p1.x, dA); dA = fmaf(a1.y, p1.y, dA); dA = fmaf(a1.z, p1.z, dA); dA = fmaf(a1.w, p1.w, dA);
  dA = fmaf(a2.x, p2.x, dA); dA = fmaf(a2.y, p2.y, dA); dA = fmaf(a2.z, p2.z, dA); dA = fmaf(a2.w, p2.w, dA);
  dA = fmaf(a3.x, p3.x, dA); dA = fmaf(a3.y, p3.y, dA); dA = fmaf(a3.z, p3.z, dA); dA = fmaf(a3.w, p3.w, dA);
  dB = fmaf(b0.x, p0.x, dB); dB = fmaf(b0.y, p0.y, dB); dB = fmaf(b0.z, p0.z, dB); dB = fmaf(b0.w, p0.w, dB);
  dB = fmaf(b1.x, p1.x, dB); dB = fmaf(b1.y, p1.y, dB); dB = fmaf(b1.z, p1.z, dB); dB = fmaf(b1.w, p1.w, dB);
  dB = fmaf(b2.x, p2.x, dB); dB = fmaf(b2.y, p2.y, dB); dB = fmaf(b2.z, p2.z, dB); dB = fmaf(b2.w, p2.w, dB);
  dB = fmaf(b3.x, p3.x, dB); dB = fmaf(b3.y, p3.y, dB); dB = fmaf(b3.z, p3.z, dB); dB = fmaf(b3.w, p3.w, dB);
  pp = fmaf(p0.x, p0.x, pp); pp = fmaf(p0.y, p0.y, pp); pp = fmaf(p0.z, p0.z, pp); pp = fmaf(p0.w, p0.w, pp);
  pp = fmaf(p1.x, p1.x, pp); pp = fmaf(p1.y, p1.y, pp); pp = fmaf(p1.z, p1.z, pp); pp = fmaf(p1.w, p1.w, pp);
  pp = fmaf(p2.x, p2.x, pp); pp = fmaf(p2.y, p2.y, pp); pp = fmaf(p2.z, p2.z, pp); pp = fmaf(p2.w, p2.w, pp);
  pp = fmaf(p3.x, p3.x, pp); pp = fmaf(p3.y, p3.y, pp); pp = fmaf(p3.z, p3.z, pp); pp = fmaf(p3.w, p3.w, pp);
#pragma unroll
  for (int off = 4; off > 0; off >>= 1) {
    dA += __shfl_down(dA, off, 8);
    dB += __shfl_down(dB, off, 8);
    pp += __shfl_down(pp, off, 8);
  }
  if (l8 == 0) {
    float pni = 1.0f / sqrtf(pp);
    if (vA) {
      float s = tanhf(dA * pni);
      score[rA] = s;
      unsigned k = okey(s);
      keys[rA] = k;
      atomicAdd(&bins[k >> 16], 1u);
    }
    if (vB) {
      float s = tanhf(dB * pni);
      score[rB] = s;
      unsigned k = okey(s);
      keys[rB] = k;
      atomicAdd(&bins[k >> 16], 1u);
    }
  }
}

// ---------- findbin (block 0) + edge slice ----------
__global__ __launch_bounds__(1024) void findbin_edge_kernel(const unsigned* __restrict__ bins,
                                                            unsigned* __restrict__ thrB,
                                                            const int* __restrict__ ei,
                                                            const float* __restrict__ ew,
                                                            unsigned long long* __restrict__ cnt64,
                                                            unsigned short* __restrict__ eslot,
                                                            int E, int ebase, int elim) {
  if (blockIdx.x > 0) {
    edge_slice(ei, ew, cnt64, eslot, E, ebase + ((int)blockIdx.x - 1) * 1024 + (int)threadIdx.x, elim);
    return;
  }
  __shared__ unsigned csum[1024];
  int t = threadIdx.x;
  unsigned hv[64];
  unsigned s = 0;
  const unsigned* bp = bins + t * 64;
#pragma unroll
  for (int b = 0; b < 64; ++b) { hv[b] = bp[b]; s += hv[b]; }
  csum[t] = s;
  __syncthreads();
  for (int st = 1; st < 1024; st <<= 1) {
    unsigned add = (t + st < 1024) ? csum[t + st] : 0u;
    __syncthreads();
    csum[t] += add;
    __syncthreads();
  }
  unsigned mySum = csum[t];
  unsigned above = (t == 1023) ? 0u : csum[t + 1];
  if (mySum >= (unsigned)TK && above < (unsigned)TK) {
    unsigned cum = above;
    int b = 63;
    for (; b > 0; --b) {
      unsigned h = hv[b];
      if (cum + h >= (unsigned)TK) break;
      cum += h;
    }
    thrB[0] = (unsigned)(t * 64 + b);
  }
}

// ---------- compact candidates (blocks < nOwn) + edge slice ----------
__global__ __launch_bounds__(1024) void compact_edge_kernel(const unsigned* __restrict__ keys,
                                                            const unsigned* __restrict__ thrB,
                                                            int* __restrict__ ncnt,
                                                            int* __restrict__ candIdx, int n, int nOwn,
                                                            const int* __restrict__ ei,
                                                            const float* __restrict__ ew,
                                                            unsigned long long* __restrict__ cnt64,
                                                            unsigned short* __restrict__ eslot,
                                                            int E, int ebase, int elim) {
  if ((int)blockIdx.x >= nOwn) {
    edge_slice(ei, ew, cnt64, eslot, E,
               ebase + ((int)blockIdx.x - nOwn) * 1024 + (int)threadIdx.x, elim);
    return;
  }
  int i = blockIdx.x * 1024 + threadIdx.x;
  if (i < n) {
    if ((keys[i] >> 16) >= thrB[0]) {
      int pos = atomicAdd(ncnt, 1);
      candIdx[pos] = i;
    }
  }
}

// ---------- exact top-K select (block 0) + edge slice ----------
#define CCAP 6144
__global__ __launch_bounds__(1024) void select_edge_kernel(const unsigned* __restrict__ keys,
                                                           const int* __restrict__ candIdx,
                                                           const int* __restrict__ ncp,
                                                           const float* __restrict__ score,
                                                           int* __restrict__ perm,
                                                           float* __restrict__ tsc,
                                                           const int* __restrict__ ei,
                                                           const float* __restrict__ ew,
                                                           unsigned long long* __restrict__ cnt64,
                                                           unsigned short* __restrict__ eslot,
                                                           int E, int ebase, int elim) {
  if (blockIdx.x > 0) {
    edge_slice(ei, ew, cnt64, eslot, E, ebase + ((int)blockIdx.x - 1) * 1024 + (int)threadIdx.x, elim);
    return;
  }
  __shared__ unsigned sk[CCAP];
  __shared__ int si[CCAP];
  int nc = ncp[0];
  int t = threadIdx.x;
  int m = nc < CCAP ? nc : CCAP;
  for (int i = t; i < m; i += 1024) {
    int ci = candIdx[i];
    si[i] = ci;
    sk[i] = keys[ci];
  }
  __syncthreads();
  for (int ci = t; ci < nc; ci += 1024) {
    unsigned mk;
    int mi;
    if (ci < CCAP) { mk = sk[ci]; mi = si[ci]; }
    else { mi = candIdx[ci]; mk = keys[mi]; }
    int rank = 0;
    for (int j = 0; j < m; ++j) {
      unsigned kj = sk[j];
      int ij = si[j];
      rank += (kj > mk || (kj == mk && ij < mi)) ? 1 : 0;
    }
    for (int j = CCAP; j < nc; ++j) {
      int ij = candIdx[j];
      unsigned kj = keys[ij];
      rank += (kj > mk || (kj == mk && ij < mi)) ? 1 : 0;
    }
    if (rank < TK) {
      perm[rank] = mi;
      tsc[rank] = score[mi];
    }
  }
}

// ---------- GRU (blocks < 128, 128 thr) + edge slice; writes W transposed ----------
__global__ void gru_edge_kernel(const float* __restrict__ x, const int* __restrict__ perm,
                                const float* __restrict__ tsc, const float* __restrict__ W0,
                                const float* __restrict__ w_ih, const float* __restrict__ w_hh,
                                const float* __restrict__ b_ih, const float* __restrict__ b_hh,
                                float* __restrict__ WT,
                                const int* __restrict__ ei, const float* __restrict__ ew,
                                unsigned long long* __restrict__ cnt64,
                                unsigned short* __restrict__ eslot, int E, int ebase, int elim) {
  if ((int)blockIdx.x >= NF) {
    edge_slice(ei, ew, cnt64, eslot, E, ebase + ((int)blockIdx.x - NF) * 128 + (int)threadIdx.x, elim);
    return;
  }
  __shared__ float xs[NF], w0s[NF];
  int i = blockIdx.x, j = threadIdx.x;
  int pi = perm[i];
  float s = tsc[i];
  xs[j] = x[(size_t)pi * NF + j] * s;
  w0s[j] = W0[i * NF + j];
  __syncthreads();
  float gir = b_ih[j], giz = b_ih[NF + j], gin = b_ih[2 * NF + j];
  float ghr = b_hh[j], ghz = b_hh[NF + j], ghn = b_hh[2 * NF + j];
  const float* wr = w_ih + (size_t)j * NF;
  const float* wz = w_ih + (size_t)(NF + j) * NF;
  const float* wn = w_ih + (size_t)(2 * NF + j) * NF;
  const float* ur = w_hh + (size_t)j * NF;
  const float* uz = w_hh + (size_t)(NF + j) * NF;
  const float* un = w_hh + (size_t)(2 * NF + j) * NF;
#pragma unroll 4
  for (int k = 0; k < NF; ++k) {
    float xv = xs[k], wv = w0s[k];
    gir = fmaf(xv, wr[k], gir);
    giz = fmaf(xv, wz[k], giz);
    gin = fmaf(xv, wn[k], gin);
    ghr = fmaf(wv, ur[k], ghr);
    ghz = fmaf(wv, uz[k], ghz);
    ghn = fmaf(wv, un[k], ghn);
  }
  float r = 1.0f / (1.0f + expf(-(gir + ghr)));
  float z = 1.0f / (1.0f + expf(-(giz + ghz)));
  float nn = tanhf(gin + r * ghn);
  WT[(size_t)j * NF + i] = (1.0f - z) * nn + z * w0s[j];  // transposed: WT[n][k]
}

// ---------- scan over counts (block-local exclusive) + dinv ----------
#define SCAN_B 1024
__global__ __launch_bounds__(1024) void scan1_kernel(const unsigned long long* __restrict__ cnt64,
                                                     int* __restrict__ offL, int* __restrict__ bsum,
                                                     float* __restrict__ dinv, int n) {
  __shared__ int sd[SCAN_B];
  int t = threadIdx.x;
  int i = blockIdx.x * SCAN_B + t;
  int v = 0;
  if (i < n) {
    unsigned long long cv = cnt64[i];
    v = (int)(cv >> 32);
    float dsum = (float)((unsigned)cv) * (1.0f / 16777216.0f) + 1.0f;  // + self-loop
    dinv[i] = 1.0f / sqrtf(dsum);
  }
  sd[t] = v;
  __syncthreads();
  for (int s = 1; s < SCAN_B; s <<= 1) {
    int add = (t >= s) ? sd[t - s] : 0;
    __syncthreads();
    sd[t] += add;
    __syncthreads();
  }
  if (i <= n) offL[i] = sd[t] - v;  // block-local exclusive
  if (t == SCAN_B - 1) bsum[blockIdx.x] = sd[t];
}

// ---------- tiny: wave-scan of bsum -> bexc ----------
__global__ void scan2_kernel(const int* __restrict__ bsum, int* __restrict__ bexc, int nb) {
  int t = threadIdx.x;
  if (t < 64) {  // requires nb <= 63 (N <= 64K)
    int v = (t < nb) ? bsum[t] : 0;
    int incl = v;
#pragma unroll
    for (int s = 1; s < 64; s <<= 1) {
      int u = __shfl_up(incl, s, 64);
      if (t >= s) incl += u;
    }
    if (t <= nb) bexc[t] = incl - v;
  }
}

// ---------- GEMM1 (x f32 -> xw fp16) fused with CSR fill ----------
__global__ __launch_bounds__(256) void gemm1_fill_kernel(const float* __restrict__ x,
                                                         const float* __restrict__ Bt,
                                                         unsigned* __restrict__ Ch, int nrows,
                                                         int nbGemm,
                                                         const int* __restrict__ ei,
                                                         const float* __restrict__ ew,
                                                         const float* __restrict__ dinv,
                                                         const int* __restrict__ offL,
                                                         const int* __restrict__ bexc,
                                                         const unsigned short* __restrict__ eslot,
                                                         unsigned* __restrict__ epair, int E) {
  __shared__ char ldsA[64 * 256];
  __shared__ char ldsB[128 * 256];
  if ((int)blockIdx.x >= nbGemm) {
    int e = ((int)blockIdx.x - nbGemm) * 256 + (int)threadIdx.x;
    if (e < E) {
      int r = ei[e], c = ei[E + e];
      int pos = offL[c] + bexc[c >> 10] + (int)eslot[e];
      float cf = dinv[r] * ew[e] * dinv[c];
      unsigned hb = (unsigned)__builtin_bit_cast(unsigned short, __float2half(cf));
      epair[pos] = (unsigned)r | (hb << 16);
    }
    return;
  }
  const int t = threadIdx.x;
  const int row0 = blockIdx.x * 64;
  {  // stage Bt -> fp16 LDS
    const float2* B2 = (const float2*)Bt;
#pragma unroll
    for (int i = 0; i < 32; ++i) {
      int idx = i * 256 + t;
      int nn = idx >> 6, kp = idx & 63;
      float2 v = B2[idx];
      __half2 h = __floats2half2_rn(v.x, v.y);
      int byte = (nn * 256 + kp * 4) ^ ((nn & 7) << 4);
      *(unsigned*)&ldsB[byte] = *(unsigned*)&h;
    }
  }
  {  // stage A (f32 -> fp16)
    const float2* A2 = (const float2*)x;
#pragma unroll
    for (int i = 0; i < 16; ++i) {
      int idx = i * 256 + t;
      int r = idx >> 6, cp = idx & 63;
      int gr = row0 + r;
      float2 v = make_float2(0.f, 0.f);
      if (gr < nrows) v = A2[(size_t)gr * 64 + cp];
      __half2 h = __floats2half2_rn(v.x, v.y);
      int byte = (r * 256 + cp * 4) ^ ((r & 7) << 4);
      *(unsigned*)&ldsA[byte] = *(unsigned*)&h;
    }
  }
  __syncthreads();
  const int wave = t >> 6, l = t & 63;
  const int wr0 = wave * 16;
  const int lm = l & 15, q = l >> 4;
  floatx4 acc[8];
#pragma unroll
  for (int nt = 0; nt < 8; ++nt) acc[nt] = (floatx4){0.f, 0.f, 0.f, 0.f};
#pragma unroll
  for (int ks = 0; ks < 4; ++ks) {
    int arow = wr0 + lm;
    half8 a = *(const half8*)&ldsA[(arow * 256 + ks * 64 + q * 16) ^ ((arow & 7) << 4)];
#pragma unroll
    for (int nt = 0; nt < 8; ++nt) {
      int nn = nt * 16 + lm;
      half8 b = *(const half8*)&ldsB[(nn * 256 + ks * 64 + q * 16) ^ ((nn & 7) << 4)];
      acc[nt] = __builtin_amdgcn_mfma_f32_16x16x32_f16(a, b, acc[nt], 0, 0, 0);
    }
  }
#pragma unroll
  for (int nt = 0; nt < 8; ++nt) {
    int col = nt * 16 + lm;
#pragma unroll
    for (int r = 0; r < 4; ++r) {
      int gr = row0 + wr0 + q * 4 + r;
      if (gr < nrows)
        ((__half*)Ch)[(size_t)gr * NF + col] = __float2half(acc[nt][r]);
    }
  }
}

// ---------- aggregate: one wave per node, 8 gathers in flight, relu + fp16 out ----------
__global__ void aggregate_kernel(const unsigned* __restrict__ epair, const int* __restrict__ offL,
                                 const int* __restrict__ bexc, const float* __restrict__ dinv,
                                 const uint4* __restrict__ xw4, unsigned* __restrict__ hh, int n) {
  int w = (int)((blockIdx.x * (size_t)blockDim.x + threadIdx.x) >> 6);
  if (w >= n) return;
  int lane = threadIdx.x & 63;
  int q = lane >> 4, l16 = lane & 15;
  int n0 = offL[w] + bexc[w >> 10];
  int n1 = offL[w + 1] + bexc[(w + 1) >> 10];
  float acc[8] = {0.f, 0.f, 0.f, 0.f, 0.f, 0.f, 0.f, 0.f};
  if (q == 0) {
    float dv = dinv[w];
    float c2 = dv * dv;  // self-loop: dinv[i]*1.0*dinv[i]
    uint4 su = xw4[(size_t)w * 16 + l16];
    float2 f0 = __half22float2(*(const __half2*)&su.x);
    float2 f1 = __half22float2(*(const __half2*)&su.y);
    float2 f2 = __half22float2(*(const __half2*)&su.z);
    float2 f3 = __half22float2(*(const __half2*)&su.w);
    acc[0] = c2 * f0.x; acc[1] = c2 * f0.y; acc[2] = c2 * f1.x; acc[3] = c2 * f1.y;
    acc[4] = c2 * f2.x; acc[5] = c2 * f2.y; acc[6] = c2 * f3.x; acc[7] = c2 * f3.y;
  }
  int e = n0 + q;
  for (; e + 4 < n1; e += 8) {
    unsigned p0 = epair[e], p1 = epair[e + 4];
    uint4 u0 = xw4[(size_t)(p0 & 0xFFFFu) * 16 + l16];
    uint4 u1 = xw4[(size_t)(p1 & 0xFFFFu) * 16 + l16];
    float c0 = __half2float(__builtin_bit_cast(__half, (unsigned short)(p0 >> 16)));
    float c1 = __half2float(__builtin_bit_cast(__half, (unsigned short)(p1 >> 16)));
    float2 f0, f1, f2, f3;
    f0 = __half22float2(*(const __half2*)&u0.x); f1 = __half22float2(*(const __half2*)&u0.y);
    f2 = __half22float2(*(const __half2*)&u0.z); f3 = __half22float2(*(const __half2*)&u0.w);
    acc[0] = fmaf(c0, f0.x, acc[0]); acc[1] = fmaf(c0, f0.y, acc[1]);
    acc[2] = fmaf(c0, f1.x, acc[2]); acc[3] = fmaf(c0, f1.y, acc[3]);
    acc[4] = fmaf(c0, f2.x, acc[4]); acc[5] = fmaf(c0, f2.y, acc[5]);
    acc[6] = fmaf(c0, f3.x, acc[6]); acc[7] = fmaf(c0, f3.y, acc[7]);
    f0 = __half22float2(*(const __half2*)&u1.x); f1 = __half22float2(*(const __half2*)&u1.y);
    f2 = __half22float2(*(const __half2*)&u1.z); f3 = __half22float2(*(const __half2*)&u1.w);
    acc[0] = fmaf(c1, f0.x, acc[0]); acc[1] = fmaf(c1, f0.y, acc[1]);
    acc[2] = fmaf(c1, f1.x, acc[2]); acc[3] = fmaf(c1, f1.y, acc[3]);
    acc[4] = fmaf(c1, f2.x, acc[4]); acc[5] = fmaf(c1, f2.y, acc[5]);
    acc[6] = fmaf(c1, f3.x, acc[6]); acc[7] = fmaf(c1, f3.y, acc[7]);
  }
  for (; e < n1; e += 4) {
    unsigned p0 = epair[e];
    uint4 u0 = xw4[(size_t)(p0 & 0xFFFFu) * 16 + l16];
    float c0 = __half2float(__builtin_bit_cast(__half, (unsigned short)(p0 >> 16)));
    float2 f0 = __half22float2(*(const __half2*)&u0.x);
    float2 f1 = __half22float2(*(const __half2*)&u0.y);
    float2 f2 = __half22float2(*(const __half2*)&u0.z);
    float2 f3 = __half22float2(*(const __half2*)&u0.w);
    acc[0] = fmaf(c0, f0.x, acc[0]); acc[1] = fmaf(c0, f0.y, acc[1]);
    acc[2] = fmaf(c0, f1.x, acc[2]); acc[3] = fmaf(c0, f1.y, acc[3]);
    acc[4] = fmaf(c0, f2.x, acc[4]); acc[5] = fmaf(c0, f2.y, acc[5]);
    acc[6] = fmaf(c0, f3.x, acc[6]); acc[7] = fmaf(c0, f3.y, acc[7]);
  }
#pragma unroll
  for (int j = 0; j < 8; ++j) {
    float a = acc[j];
    a += __shfl_xor(a, 16, 64);
    a += __shfl_xor(a, 32, 64);
    acc[j] = a;
  }
  if (q == 0) {
    __half2 h0 = __floats2half2_rn(fmaxf(acc[0], 0.f), fmaxf(acc[1], 0.f));
    __half2 h1 = __floats2half2_rn(fmaxf(acc[2], 0.f), fmaxf(acc[3], 0.f));
    __half2 h2 = __floats2half2_rn(fmaxf(acc[4], 0.f), fmaxf(acc[5], 0.f));
    __half2 h3 = __floats2half2_rn(fmaxf(acc[6], 0.f), fmaxf(acc[7], 0.f));
    uint4 o;
    o.x = *(unsigned*)&h0; o.y = *(unsigned*)&h1; o.z = *(unsigned*)&h2; o.w = *(unsigned*)&h3;
    *(uint4*)&hh[(size_t)w * 64 + l16 * 4] = o;
  }
}

// ---------- MFMA GEMM (generic): C[m][n] = sum_k A[m][k]*Bt[n][k] ----------
template <int HIN, int HOUT, int BIAS>
__global__ __launch_bounds__(256) void gemm_mfma_kernel(const void* __restrict__ Ap,
                                                        const float* __restrict__ Bt,
                                                        const float* __restrict__ bias,
                                                        void* __restrict__ Cp, int nrows) {
  __shared__ char ldsA[64 * 256];
  __shared__ char ldsB[128 * 256];
  const int t = threadIdx.x;
  const int row0 = blockIdx.x * 64;
  {
    const float2* B2 = (const float2*)Bt;
#pragma unroll
    for (int i = 0; i < 32; ++i) {
      int idx = i * 256 + t;
      int nn = idx >> 6, kp = idx & 63;
      float2 v = B2[idx];
      __half2 h = __floats2half2_rn(v.x, v.y);
      int byte = (nn * 256 + kp * 4) ^ ((nn & 7) << 4);
      *(unsigned*)&ldsB[byte] = *(unsigned*)&h;
    }
  }
  if (HIN) {
    const unsigned* Ah = (const unsigned*)Ap;
#pragma unroll
    for (int i = 0; i < 16; ++i) {
      int idx = i * 256 + t;
      int r = idx >> 6, cp = idx & 63;
      int gr = row0 + r;
      unsigned v = (gr < nrows) ? Ah[(size_t)gr * 64 + cp] : 0u;
      int byte = (r * 256 + cp * 4) ^ ((r & 7) << 4);
      *(unsigned*)&ldsA[byte] = v;
    }
  } else {
    const float2* A2 = (const float2*)Ap;
#pragma unroll
    for (int i = 0; i < 16; ++i) {
      int idx = i * 256 + t;
      int r = idx >> 6, cp = idx & 63;
      int gr = row0 + r;
      float2 v = make_float2(0.f, 0.f);
      if (gr < nrows) v = A2[(size_t)gr * 64 + cp];
      __half2 h = __floats2half2_rn(v.x, v.y);
      int byte = (r * 256 + cp * 4) ^ ((r & 7) << 4);
      *(unsigned*)&ldsA[byte] = *(unsigned*)&h;
    }
  }
  __syncthreads();
  const int wave = t >> 6, l = t & 63;
  const int wr0 = wave * 16;
  const int lm = l & 15, q = l >> 4;
  floatx4 acc[8];
#pragma unroll
  for (int nt = 0; nt < 8; ++nt) acc[nt] = (floatx4){0.f, 0.f, 0.f, 0.f};
#pragma unroll
  for (int ks = 0; ks < 4; ++ks) {
    int arow = wr0 + lm;
    half8 a = *(const half8*)&ldsA[(arow * 256 + ks * 64 + q * 16) ^ ((arow & 7) << 4)];
#pragma unroll
    for (int nt = 0; nt < 8; ++nt) {
      int nn = nt * 16 + lm;
      half8 b = *(const half8*)&ldsB[(nn * 256 + ks * 64 + q * 16) ^ ((nn & 7) << 4)];
      acc[nt] = __builtin_amdgcn_mfma_f32_16x16x32_f16(a, b, acc[nt], 0, 0, 0);
    }
  }
#pragma unroll
  for (int nt = 0; nt < 8; ++nt) {
    int col = nt * 16 + lm;
    float bv = BIAS ? bias[col] : 0.f;
#pragma unroll
    for (int r = 0; r < 4; ++r) {
      int gr = row0 + wr0 + q * 4 + r;
      if (gr < nrows) {
        float v = acc[nt][r] + bv;
        if (HOUT) ((__half*)Cp)[(size_t)gr * NF + col] = __float2half(v);
        else ((float*)Cp)[(size_t)gr * NF + col] = v;
      }
    }
  }
}

extern "C" void kernel_launch(void* const* d_in, const int* in_sizes, int n_in,
                              void* d_out, int out_size, void* d_ws, size_t ws_size,
                              hipStream_t stream) {
  const float* x = (const float*)d_in[0];
  const int* ei = (const int*)d_in[1];
  const float* ew = (const float*)d_in[2];
  const float* p = (const float*)d_in[3];
  const float* w_ih = (const float*)d_in[4];
  const float* w_hh = (const float*)d_in[5];
  const float* b_ih = (const float*)d_in[6];
  const float* b_hh = (const float*)d_in[7];
  const float* W0 = (const float*)d_in[8];
  const float* W_lin = (const float*)d_in[9];
  const float* b_lin = (const float*)d_in[10];
  float* out = (float*)d_out;

  const int N = in_sizes[0] / NF;  // 50000 (< 65536 required for 16-bit rows)
  const int E = in_sizes[1] / 2;   // 800000

  char* w = (char*)d_ws;
  unsigned* xwh = (unsigned*)w;                                 // N*64 (fp16 xw)
  unsigned* hh = xwh + (size_t)N * 64;                          // N*64 (fp16 relu(h))
  float* score = (float*)(hh + (size_t)N * 64);                 // N
  unsigned* keys = (unsigned*)(score + N);                      // N
  unsigned long long* cnt64 = (unsigned long long*)(keys + N);  // ZERO region: N x 8B
  unsigned* bins = (unsigned*)(cnt64 + N);                      // 65536
  int* ncnt = (int*)(bins + 65536);                             // 1 (end of ZERO region)
  float* dinv = (float*)(ncnt + 1);                             // N
  unsigned* thrB = (unsigned*)(dinv + N);                       // 1
  int* candIdx = (int*)(thrB + 1);                              // N
  int* offL = candIdx + N;                                      // N+1
  int* bsum = offL + N + 1;                                     // 64
  int* bexc = bsum + 64;                                        // 64
  unsigned short* eslot = (unsigned short*)(bexc + 64);         // E x 2B
  unsigned* epair = (unsigned*)(eslot + E);                     // E x 4B
  float* WevT = (float*)(epair + E);                            // 128*128
  int* perm = (int*)(WevT + NF * NF);                           // 128
  float* tsc = (float*)(perm + NF);                             // 128

  const int nb = (N + SCAN_B - 1) / SCAN_B;
  const int nbEdge = (E + 255) / 256;
  const int nbGemm = (N + 63) / 64;
  const int nbScore = (N + 63) / 64;
  const int nOwnC = (N + 1023) / 1024;

  // edge-slice partition: 45% rides with score, remaining 55% over 4 stages
  const int eA1 = (int)(((long long)E * 9) / 20);
  const int perR = (E - eA1 + 3) / 4;
  const int eB1 = (eA1 + perR < E) ? eA1 + perR : E;
  const int eC1 = (eB1 + perR < E) ? eB1 + perR : E;
  const int eD1 = (eC1 + perR < E) ? eC1 + perR : E;
  const int bSA = (eA1 + 255) / 256;
  const int bSB = (eB1 - eA1 + 1023) / 1024;
  const int bSC = (eC1 - eB1 + 1023) / 1024;
  const int bSD = (eD1 - eC1 + 1023) / 1024;
  const int bSE = (E - eD1 + 127) / 128;

  // zero region: cnt64 (N*8) + bins (256KB) + ncnt, padded to 16B
  const int n4zero = (N * 8 + 65536 * 4 + 4 + 15) / 16;

  zero_kernel<<<64, 1024, 0, stream>>>((uint4*)cnt64, n4zero);
  score_edge_kernel<<<nbScore + bSA, 256, 0, stream>>>(x, p, score, keys, bins, N, nbScore,
                                                       ei, ew, cnt64, eslot, E, 0, eA1);
  findbin_edge_kernel<<<1 + bSB, 1024, 0, stream>>>(bins, thrB, ei, ew, cnt64, eslot, E, eA1, eB1);
  compact_edge_kernel<<<nOwnC + bSC, 1024, 0, stream>>>(keys, thrB, ncnt, candIdx, N, nOwnC,
                                                        ei, ew, cnt64, eslot, E, eB1, eC1);
  select_edge_kernel<<<1 + bSD, 1024, 0, stream>>>(keys, candIdx, ncnt, score, perm, tsc,
                                                   ei, ew, cnt64, eslot, E, eC1, eD1);
  gru_edge_kernel<<<NF + bSE, NF, 0, stream>>>(x, perm, tsc, W0, w_ih, w_hh, b_ih, b_hh, WevT,
                                               ei, ew, cnt64, eslot, E, eD1, E);
  scan1_kernel<<<nb, SCAN_B, 0, stream>>>(cnt64, offL, bsum, dinv, N);
  scan2_kernel<<<1, 64, 0, stream>>>(bsum, bexc, nb);
  gemm1_fill_kernel<<<nbGemm + nbEdge, 256, 0, stream>>>(x, WevT, xwh, N, nbGemm,
                                                         ei, ew, dinv, offL, bexc, eslot, epair, E);
  aggregate_kernel<<<(N + 3) / 4, 256, 0, stream>>>(epair, offL, bexc, dinv,
                                                    (const uint4*)xwh, hh, N);
  gemm_mfma_kernel<1, 0, 1><<<nbGemm, 256, 0, stream>>>(hh, W_lin, b_lin, out, N);
}